// Round 22
// baseline (746.372 us; speedup 1.0000x reference)
//
#include <hip/hip_runtime.h>
#include <math.h>

#define N_NODES 50000
#define N_EDGES 400000
#define CH      256
#define NNZ     800000

typedef short s16x8 __attribute__((ext_vector_type(8)));
typedef float f32x4 __attribute__((ext_vector_type(4)));

__device__ __forceinline__ float sigmoidf_(float x) {
    return 1.0f / (1.0f + __expf(-x));
}
__device__ __forceinline__ unsigned short f2bf(float f) {
    unsigned u = __float_as_uint(f);
    u = (u + 0x7FFFu + ((u >> 16) & 1u)) >> 16;   // RNE
    return (unsigned short)u;
}
__device__ __forceinline__ float bf2f(unsigned short h) {
    return __uint_as_float((unsigned)h << 16);
}
__device__ __forceinline__ f32x4 bfrow(ushort4 s) {
    f32x4 r;
    r.x = bf2f(s.x); r.y = bf2f(s.y); r.z = bf2f(s.z); r.w = bf2f(s.w);
    return r;
}

// ---------------------------------------------------------------------------
__global__ __launch_bounds__(256) void fill_i32(int* __restrict__ p, int val, int n)
{
    int stride = gridDim.x * 256;
    for (int i = blockIdx.x * 256 + threadIdx.x; i < n; i += stride) p[i] = val;
}

// --------------------- scan-free CSR build, rank/placement split ------------
__global__ __launch_bounds__(256) void hist_cvt(
    const int* __restrict__ k0, int* __restrict__ c0, int* __restrict__ r0,
    const int* __restrict__ k1, int* __restrict__ c1, int* __restrict__ r1,
    const int* __restrict__ k2, int* __restrict__ c2, int* __restrict__ r2, int n,
    const float* __restrict__ W00, const float* __restrict__ W01,
    const float* __restrict__ W10, const float* __restrict__ W11,
    unsigned short* __restrict__ Wp00, unsigned short* __restrict__ Wp01,
    unsigned short* __restrict__ Wh10, unsigned short* __restrict__ Wl10,
    unsigned short* __restrict__ Wh11, unsigned short* __restrict__ Wl11)
{
    int y = blockIdx.y;
    if (y < 3) {
        int i = blockIdx.x * 256 + threadIdx.x;
        if (i >= n) return;
        if      (y == 0) r0[i] = atomicAdd(&c0[k0[i]], 1);
        else if (y == 1) r1[i] = atomicAdd(&c1[k1[i]], 1);
        else             r2[i] = atomicAdd(&c2[k2[i]], 1);
        return;
    }
    int x = blockIdx.x;
    if (x >= 1024) return;
    int variant = x >> 8, nn = x & 255, k = threadIdx.x;
    int k0i = k >> 5, g = (k >> 3) & 3, j = k & 7;
    size_t o = (((size_t)(k0i * 4 + g)) * 256 + nn) * 8 + j;
    if (variant == 0) { Wp00[o] = f2bf(W00[k * 256 + nn]); return; }
    if (variant == 1) { Wp01[o] = f2bf(W01[k * 256 + nn]); return; }
    const float* W = (variant == 2) ? W10 : W11;
    unsigned short* Th = (variant == 2) ? Wh10 : Wh11;
    unsigned short* Tl = (variant == 2) ? Wl10 : Wl11;
    float w = W[k * 256 + nn];
    unsigned short h = f2bf(w);
    Th[o] = h;
    Tl[o] = f2bf(w - bf2f(h));
}

__global__ __launch_bounds__(256) void reserve3(
    int* __restrict__ c0, int* __restrict__ sd0, int n0,
    int* __restrict__ c1, int* __restrict__ sd1, int n1,
    int* __restrict__ c2, int* __restrict__ sd2, int n2,
    int* __restrict__ cursors)
{
    int y = blockIdx.y;
    int* cnt = (y == 0) ? c0 : (y == 1) ? c1 : c2;
    int* sd  = (y == 0) ? sd0 : (y == 1) ? sd1 : sd2;
    int  nk  = (y == 0) ? n0 : (y == 1) ? n1 : n2;
    int k = blockIdx.x * 256 + threadIdx.x;
    if (k >= nk) return;
    int deg  = cnt[k];
    int base = deg ? atomicAdd(&cursors[y], deg) : 0;
    sd[k]  = base | (deg << 20);
    cnt[k] = base;
}

__global__ __launch_bounds__(256) void scatter3(
    const int* __restrict__ k0, const int* __restrict__ o0, const float* __restrict__ v0,
    const int* __restrict__ c0, const int* __restrict__ r0, int2* __restrict__ cv0,
    const int* __restrict__ k1, const int* __restrict__ o1, const float* __restrict__ v1,
    const int* __restrict__ c1, const int* __restrict__ r1, int2* __restrict__ cv1,
    const int* __restrict__ k2, const int* __restrict__ o2, const float* __restrict__ v2,
    const int* __restrict__ c2, const int* __restrict__ r2, int2* __restrict__ cv2,
    const int* __restrict__ sd_e, int n)
{
    int i = blockIdx.x * 256 + threadIdx.x;
    if (i >= n) return;
    if (blockIdx.y == 0) {
        int pos = c0[k0[i]] + r0[i];
        cv0[pos] = make_int2(o0[i], __float_as_int(v0[i]));
    } else if (blockIdx.y == 1) {
        int pos = c1[k1[i]] + r1[i];
        cv1[pos] = make_int2(o1[i], __float_as_int(v1[i]));
    } else {
        int pos = c2[k2[i]] + r2[i];
        cv2[pos] = make_int2(sd_e[o2[i]], __float_as_int(v2[i]));  // pre-resolved
    }
}

// ---------------------------------------------------------------------------
// Fused dual-output MFMA GEMM, weight-stationary via LDS.
// ---------------------------------------------------------------------------
__global__ __launch_bounds__(256, 2) void mfma_gemm2(
    const float* __restrict__ X,
    const unsigned short* __restrict__ Wp0, const unsigned short* __restrict__ Wp1,
    unsigned short* __restrict__ Y0, unsigned short* __restrict__ Y1, int M)
{
    __shared__ unsigned short lds[2 * 4 * 257 * 8];   // 32896 B
    const int tid = threadIdx.x;
    const int wv = tid >> 6, lane = tid & 63;
    const int row0 = blockIdx.x * 64 + wv * 16;
    const int r = lane & 15, g = lane >> 4;

    f32x4 acc0[16], acc1[16];
#pragma unroll
    for (int t = 0; t < 16; t++) {
        acc0[t] = (f32x4){0.f, 0.f, 0.f, 0.f};
        acc1[t] = (f32x4){0.f, 0.f, 0.f, 0.f};
    }

    int arow = row0 + r; if (arow >= M) arow = M - 1;

    for (int k0i = 0; k0i < 8; ++k0i) {
        const float* xp = X + (size_t)arow * CH + k0i * 32 + g * 8;
        float4 f0 = *(const float4*)(xp);
        float4 f1 = *(const float4*)(xp + 4);

        if (k0i) __syncthreads();
#pragma unroll
        for (int m = 0; m < 2; m++) {
            const unsigned short* src = (m == 0) ? Wp0 : Wp1;
            src += (size_t)k0i * 1024 * 8;
#pragma unroll
            for (int g2 = 0; g2 < 4; g2++) {
                int frag = (m * 4 + g2) * 257 + tid;
                *(s16x8*)&lds[frag * 8] = *(const s16x8*)(src + (size_t)(g2 * 256 + tid) * 8);
            }
        }
        __syncthreads();

        s16x8 a;
        a[0] = f2bf(f0.x); a[1] = f2bf(f0.y); a[2] = f2bf(f0.z); a[3] = f2bf(f0.w);
        a[4] = f2bf(f1.x); a[5] = f2bf(f1.y); a[6] = f2bf(f1.z); a[7] = f2bf(f1.w);

#pragma unroll
        for (int t = 0; t < 16; t++) {
            int rr = t * 16 + r;
            s16x8 b0 = *(const s16x8*)&lds[((0 + g) * 257 + rr) * 8];
            s16x8 b1 = *(const s16x8*)&lds[((4 + g) * 257 + rr) * 8];
            acc0[t] = __builtin_amdgcn_mfma_f32_16x16x32_bf16(a, b0, acc0[t], 0, 0, 0);
            acc1[t] = __builtin_amdgcn_mfma_f32_16x16x32_bf16(a, b1, acc1[t], 0, 0, 0);
        }
    }

    const int drow0 = row0 + g * 4;
#pragma unroll
    for (int t = 0; t < 16; t++) {
        int col = t * 16 + r;
#pragma unroll
        for (int j = 0; j < 4; j++) {
            int dr = drow0 + j;
            if (dr < M) {
                Y0[(size_t)dr * CH + col] = f2bf(acc0[t][j]);
                Y1[(size_t)dr * CH + col] = f2bf(acc1[t][j]);
            }
        }
    }
}

// ---------------------------------------------------------------------------
// Shared gather bodies (inlined into standalone + fused kernels; bit-identical)
// ---------------------------------------------------------------------------
__device__ __forceinline__ void gather_body(
    int r, int lane, const int* __restrict__ sd, const int2* __restrict__ cv,
    const unsigned short* __restrict__ S, void* __restrict__ O, int sig, int out_bf)
{
    unsigned sdv = (unsigned)sd[r];
    int base = (int)(sdv & 0xFFFFFu), deg = (int)(sdv >> 20);
    const unsigned lb = (unsigned)lane << 3;
    const char* Sb = (const char*)S;

    f32x4 acc = (f32x4){0.f, 0.f, 0.f, 0.f};
    int i = 0;
    for (; i + 8 <= deg; i += 8) {
        int2 e[8]; ushort4 s[8];
#pragma unroll
        for (int q = 0; q < 8; q++) e[q] = cv[base + i + q];
#pragma unroll
        for (int q = 0; q < 8; q++)
            s[q] = *(const ushort4*)(Sb + (((unsigned)e[q].x << 9) + lb));
#pragma unroll
        for (int q = 0; q < 8; q++) {
            float v = __int_as_float(e[q].y);
            f32x4 vv = {v, v, v, v};
            acc = __builtin_elementwise_fma(vv, bfrow(s[q]), acc);
        }
    }
    for (; i + 4 <= deg; i += 4) {
        int2 e[4]; ushort4 s[4];
#pragma unroll
        for (int q = 0; q < 4; q++) e[q] = cv[base + i + q];
#pragma unroll
        for (int q = 0; q < 4; q++)
            s[q] = *(const ushort4*)(Sb + (((unsigned)e[q].x << 9) + lb));
#pragma unroll
        for (int q = 0; q < 4; q++) {
            float v = __int_as_float(e[q].y);
            f32x4 vv = {v, v, v, v};
            acc = __builtin_elementwise_fma(vv, bfrow(s[q]), acc);
        }
    }
    for (; i < deg; i++) {
        int2 e = cv[base + i];
        float v = __int_as_float(e.y);
        ushort4 s = *(const ushort4*)(Sb + (((unsigned)e.x << 9) + lb));
        f32x4 vv = {v, v, v, v};
        acc = __builtin_elementwise_fma(vv, bfrow(s), acc);
    }
    if (sig) {
        acc.x = sigmoidf_(acc.x); acc.y = sigmoidf_(acc.y);
        acc.z = sigmoidf_(acc.z); acc.w = sigmoidf_(acc.w);
    }
    if (out_bf) {
        ushort4 o; o.x = f2bf(acc.x); o.y = f2bf(acc.y); o.z = f2bf(acc.z); o.w = f2bf(acc.w);
        *(ushort4*)((char*)O + (((unsigned)r << 9) + lb)) = o;
    } else {
        *(f32x4*)((char*)O + (((unsigned)r << 10) + (lb << 1))) = acc;
    }
}

__device__ __forceinline__ void edge_body(
    int n, int lane, const int* __restrict__ sd_n, const int2* __restrict__ cv_n,
    const int2* __restrict__ cv_e, const unsigned short* __restrict__ B,
    float* __restrict__ F)
{
    unsigned sdn = (unsigned)sd_n[n];
    int baseN = (int)(sdn & 0xFFFFFu), degN = (int)(sdn >> 20);
    const unsigned lb = (unsigned)lane << 3;
    const char* Bb = (const char*)B;

    f32x4 acc = (f32x4){0.f, 0.f, 0.f, 0.f};
    for (int i = 0; i < degN; i++) {
        int2 en = cv_n[baseN + i];
        unsigned sde = (unsigned)en.x;                 // pre-resolved descriptor
        float v = __int_as_float(en.y);
        int baseE = (int)(sde & 0xFFFFFu), degE = (int)(sde >> 20);

        f32x4 d = (f32x4){0.f, 0.f, 0.f, 0.f};
        int j = 0;
        for (; j + 2 <= degE; j += 2) {
            int2 e0 = cv_e[baseE + j], e1 = cv_e[baseE + j + 1];
            ushort4 b0 = *(const ushort4*)(Bb + (((unsigned)e0.x << 9) + lb));
            ushort4 b1 = *(const ushort4*)(Bb + (((unsigned)e1.x << 9) + lb));
            float u0 = __int_as_float(e0.y), u1 = __int_as_float(e1.y);
            f32x4 uv0 = {u0, u0, u0, u0};
            f32x4 uv1 = {u1, u1, u1, u1};
            d = __builtin_elementwise_fma(uv0, bfrow(b0), d);
            d = __builtin_elementwise_fma(uv1, bfrow(b1), d);
        }
        for (; j < degE; j++) {
            int2 e0 = cv_e[baseE + j];
            float u = __int_as_float(e0.y);
            ushort4 b = *(const ushort4*)(Bb + (((unsigned)e0.x << 9) + lb));
            f32x4 uv = {u, u, u, u};
            d = __builtin_elementwise_fma(uv, bfrow(b), d);
        }
        f32x4 sd4;
        sd4.x = sigmoidf_(d.x); sd4.y = sigmoidf_(d.y);
        sd4.z = sigmoidf_(d.z); sd4.w = sigmoidf_(d.w);
        f32x4 vv = {v, v, v, v};
        acc = __builtin_elementwise_fma(vv, sd4, acc);
    }
    *(f32x4*)((char*)F + (((unsigned)n << 10) + (lb << 1))) = acc;
}

// ---------------------------------------------------------------------------
// FUSED: edge branch ∥ adjacency gather-C in ONE dispatch. The two are
// mutually independent (both consume only gemm2 outputs, disjoint src/dst).
// Interleaved role bit -> latency-bound edge waves and MLP-heavy gather waves
// co-reside on every CU, filling each other's stall slots (m114 overlap).
// ---------------------------------------------------------------------------
__global__ __launch_bounds__(256) void edge_adjC_fused(
    const int* __restrict__ sd_n, const int2* __restrict__ cv_n,
    const int2* __restrict__ cv_e, const unsigned short* __restrict__ B,
    float* __restrict__ F,
    const int* __restrict__ sd_a, const int2* __restrict__ cv_a,
    const unsigned short* __restrict__ A, unsigned short* __restrict__ C,
    int n_nodes)
{
    int role = (int)(blockIdx.x & 1);
    int bid  = (int)(blockIdx.x >> 1);
    int r    = (int)(((unsigned)bid * 256u + threadIdx.x) >> 6);
    int lane = threadIdx.x & 63;
    if (r >= n_nodes) return;
    r = __builtin_amdgcn_readfirstlane(r);
    if (role == 0)
        edge_body(r, lane, sd_n, cv_n, cv_e, B, F);
    else
        gather_body(r, lane, sd_a, cv_a, A, C, 1, 1);
}

// Standalone gather (step: E = gather_adj(C), fp32 out)
__global__ __launch_bounds__(256) void gather_csr(
    const int* __restrict__ sd, const int2* __restrict__ cv,
    const unsigned short* __restrict__ S,
    void* __restrict__ O, int n_rows, int sig, int out_bf)
{
    int r    = (int)((blockIdx.x * 256u + threadIdx.x) >> 6);
    int lane = threadIdx.x & 63;
    if (r >= n_rows) return;
    r = __builtin_amdgcn_readfirstlane(r);
    gather_body(r, lane, sd, cv, S, O, sig, out_bf);
}

// ---------------------------------------------------------------------------
// Final GEMM, split-bf16 MFMA, fp32-equivalent, weight-stationary via LDS.
// FULL unroll on the t-loop (rule #20: partial unroll demotes acc to scratch).
// ---------------------------------------------------------------------------
__device__ __forceinline__ void split8(float4 a, float4 b, s16x8& hi, s16x8& lo)
{
    float v[8] = {a.x, a.y, a.z, a.w, b.x, b.y, b.z, b.w};
#pragma unroll
    for (int i = 0; i < 8; i++) {
        unsigned short h = f2bf(v[i]);
        hi[i] = (short)h;
        lo[i] = (short)f2bf(v[i] - bf2f(h));
    }
}

__global__ __launch_bounds__(256, 2) void final_mfma(
    const float* __restrict__ E, const float* __restrict__ F,
    const unsigned short* __restrict__ Wh10, const unsigned short* __restrict__ Wl10,
    const unsigned short* __restrict__ Wh11, const unsigned short* __restrict__ Wl11,
    float* __restrict__ Y, int M)
{
    __shared__ unsigned short lds[4 * 4 * 257 * 8];   // 65792 B (2 blocks/CU)
    const int tid = threadIdx.x;
    const int wv = tid >> 6, lane = tid & 63;
    const int row0 = blockIdx.x * 128 + wv * 32;
    const int r = lane & 15, g = lane >> 4;

    f32x4 acc[2][16];
#pragma unroll
    for (int gr = 0; gr < 2; gr++)
#pragma unroll
        for (int t = 0; t < 16; t++) acc[gr][t] = (f32x4){0.f, 0.f, 0.f, 0.f};

    int ar0 = row0 + r;      if (ar0 >= M) ar0 = M - 1;
    int ar1 = row0 + 16 + r; if (ar1 >= M) ar1 = M - 1;

    for (int k0i = 0; k0i < 8; ++k0i) {
        const int kbase = k0i * 32 + g * 8;
        const float* p = E + (size_t)ar0 * CH + kbase;
        float4 e0a = *(const float4*)p, e0b = *(const float4*)(p + 4);
        p = E + (size_t)ar1 * CH + kbase;
        float4 e1a = *(const float4*)p, e1b = *(const float4*)(p + 4);
        p = F + (size_t)ar0 * CH + kbase;
        float4 f0a = *(const float4*)p, f0b = *(const float4*)(p + 4);
        p = F + (size_t)ar1 * CH + kbase;
        float4 f1a = *(const float4*)p, f1b = *(const float4*)(p + 4);

        if (k0i) __syncthreads();
#pragma unroll
        for (int m = 0; m < 4; m++) {
            const unsigned short* src =
                (m == 0) ? Wh10 : (m == 1) ? Wl10 : (m == 2) ? Wh11 : Wl11;
            src += (size_t)k0i * 1024 * 8;
#pragma unroll
            for (int g2 = 0; g2 < 4; g2++) {
                int frag = (m * 4 + g2) * 257 + tid;
                *(s16x8*)&lds[frag * 8] = *(const s16x8*)(src + (size_t)(g2 * 256 + tid) * 8);
            }
        }
        __syncthreads();

        s16x8 eh0, el0, eh1, el1, fh0, fl0, fh1, fl1;
        split8(e0a, e0b, eh0, el0);
        split8(e1a, e1b, eh1, el1);
        split8(f0a, f0b, fh0, fl0);
        split8(f1a, f1b, fh1, fl1);

#pragma unroll
        for (int t = 0; t < 16; t++) {
            int rr = t * 16 + r;
            s16x8 bh0 = *(const s16x8*)&lds[((0 + g) * 257 + rr) * 8];
            s16x8 bl0 = *(const s16x8*)&lds[((4 + g) * 257 + rr) * 8];
            s16x8 bh1 = *(const s16x8*)&lds[((8 + g) * 257 + rr) * 8];
            s16x8 bl1 = *(const s16x8*)&lds[((12 + g) * 257 + rr) * 8];

            acc[0][t] = __builtin_amdgcn_mfma_f32_16x16x32_bf16(eh0, bh0, acc[0][t], 0, 0, 0);
            acc[0][t] = __builtin_amdgcn_mfma_f32_16x16x32_bf16(el0, bh0, acc[0][t], 0, 0, 0);
            acc[0][t] = __builtin_amdgcn_mfma_f32_16x16x32_bf16(eh0, bl0, acc[0][t], 0, 0, 0);
            acc[0][t] = __builtin_amdgcn_mfma_f32_16x16x32_bf16(fh0, bh1, acc[0][t], 0, 0, 0);
            acc[0][t] = __builtin_amdgcn_mfma_f32_16x16x32_bf16(fl0, bh1, acc[0][t], 0, 0, 0);
            acc[0][t] = __builtin_amdgcn_mfma_f32_16x16x32_bf16(fh0, bl1, acc[0][t], 0, 0, 0);

            acc[1][t] = __builtin_amdgcn_mfma_f32_16x16x32_bf16(eh1, bh0, acc[1][t], 0, 0, 0);
            acc[1][t] = __builtin_amdgcn_mfma_f32_16x16x32_bf16(el1, bh0, acc[1][t], 0, 0, 0);
            acc[1][t] = __builtin_amdgcn_mfma_f32_16x16x32_bf16(eh1, bl0, acc[1][t], 0, 0, 0);
            acc[1][t] = __builtin_amdgcn_mfma_f32_16x16x32_bf16(fh1, bh1, acc[1][t], 0, 0, 0);
            acc[1][t] = __builtin_amdgcn_mfma_f32_16x16x32_bf16(fl1, bh1, acc[1][t], 0, 0, 0);
            acc[1][t] = __builtin_amdgcn_mfma_f32_16x16x32_bf16(fh1, bl1, acc[1][t], 0, 0, 0);
        }
    }

#pragma unroll
    for (int gr = 0; gr < 2; gr++) {
        const int drow0 = row0 + gr * 16 + g * 4;
#pragma unroll
        for (int t = 0; t < 16; t++) {
            int col = t * 16 + r;
#pragma unroll
            for (int j = 0; j < 4; j++) {
                int dr = drow0 + j;
                if (dr < M) Y[(size_t)dr * CH + col] = sigmoidf_(acc[gr][t][j]);
            }
        }
    }
}

// ---------------------------------------------------------------------------
extern "C" void kernel_launch(void* const* d_in, const int* in_sizes, int n_in,
                              void* d_out, int out_size, void* d_ws, size_t ws_size,
                              hipStream_t stream)
{
    const float* x        = (const float*)d_in[0];
    const int*   adj_rows = (const int*)  d_in[1];
    const int*   adj_cols = (const int*)  d_in[2];
    const float* adj_vals = (const float*)d_in[3];
    const int*   inc_rows = (const int*)  d_in[4];
    const int*   inc_cols = (const int*)  d_in[5];
    const float* inc_vals = (const float*)d_in[6];
    const float* W00      = (const float*)d_in[7];
    const float* W01      = (const float*)d_in[8];
    const float* W10      = (const float*)d_in[9];
    const float* W11      = (const float*)d_in[10];

    // -------- workspace layout (~110.4 MB; proven-safe < 114.26 MB) ---------
    const size_t SZ_AB = (size_t)N_NODES * CH * 2;    // 25.6 MB
    const size_t SZ_F  = (size_t)N_NODES * CH * 4;    // 51.2 MB
    char* ws = (char*)d_ws;
    size_t off = 0;
    unsigned short* A_bf = (unsigned short*)(ws + off); off += SZ_AB;
    float*          F    = (float*)(ws + off);          off += SZ_F;
    int*   sd_a  = (int*)(ws + off);  off += (size_t)N_NODES * 4;
    int2*  cv_a  = (int2*)(ws + off); off += (size_t)NNZ * 8;
    unsigned short* Wp00  = (unsigned short*)(ws + off); off += (size_t)CH * CH * 2;
    unsigned short* Wp01  = (unsigned short*)(ws + off); off += (size_t)CH * CH * 2;
    unsigned short* Wh10  = (unsigned short*)(ws + off); off += (size_t)CH * CH * 2;
    unsigned short* Wl10  = (unsigned short*)(ws + off); off += (size_t)CH * CH * 2;
    unsigned short* Wh11  = (unsigned short*)(ws + off); off += (size_t)CH * CH * 2;
    unsigned short* Wl11  = (unsigned short*)(ws + off); off += (size_t)CH * CH * 2;
    // scratch (26.2 MB): cnt+cursors / sd / cv / rank; dead after fused kernel;
    // C_bf overlays afterwards... NOTE: C_bf is WRITTEN by the fused kernel
    // while cv_n/cv_e/sd_n are still being READ by its edge half — so C_bf
    // must NOT overlay those. C_bf overlays only the rank arrays (9.6 MB) +
    // tail; rank_* are dead after scatter3. Layout below keeps cv/sd regions
    // disjoint from C_bf.
    char* scratch = ws + off;
    int*   cnt_a   = (int*)(scratch);          // [N_NODES]
    int*   cnt_e   = cnt_a + N_NODES;          // [N_EDGES]
    int*   cnt_n   = cnt_e + N_EDGES;          // [N_NODES]
    int*   cursors = cnt_n + N_NODES;          // [64]
    int*   sd_n    = cursors + 64;             // [N_NODES]
    int*   sd_e    = sd_n + N_NODES;           // [N_EDGES]
    int2*  cv_n    = (int2*)(sd_e + N_EDGES);  // [NNZ] {descriptor, val}
    int2*  cv_e    = cv_n + NNZ;               // [NNZ] {node, val}
    int*   rank_a  = (int*)(cv_e + NNZ);       // [NNZ] — dead after scatter3
    int*   rank_e  = rank_a + NNZ;             // [NNZ]
    int*   rank_n  = rank_e + NNZ;             // [NNZ]
    // C_bf (25.6 MB) overlays rank_a onward (9.6 MB) + extends past scratch
    // tail: rank start offset within ws = off + (cnt/cursors/sd/cv = 16.6 MB).
    unsigned short* C_bf = (unsigned short*)rank_a;
    unsigned short* B_bf = (unsigned short*)d_out;
    float* E = (float*)d_out;

    const int gemm_blocks  = (N_NODES + 63) / 64;          // 782
    const int final_blocks = (N_NODES + 127) / 128;        // 391
    const int row_blocks   = (N_NODES * 64 + 255) / 256;   // 12500
    const int ent_blocks   = (NNZ + 255) / 256;            // 3125
    const int key_blocks   = (N_EDGES + 255) / 256;        // 1563

    // 0) CSR build: zero cnt+cursors -> {hist(+rank) | cvt} -> reserve -> place
    fill_i32<<<1024, 256, 0, stream>>>(cnt_a, 0, N_NODES + N_EDGES + N_NODES + 64);
    hist_cvt<<<dim3(ent_blocks, 4), 256, 0, stream>>>(
        adj_rows, cnt_a, rank_a, inc_cols, cnt_e, rank_e, inc_rows, cnt_n, rank_n, NNZ,
        W00, W01, W10, W11, Wp00, Wp01, Wh10, Wl10, Wh11, Wl11);
    reserve3<<<dim3(key_blocks, 3), 256, 0, stream>>>(
        cnt_a, sd_a, N_NODES, cnt_e, sd_e, N_EDGES, cnt_n, sd_n, N_NODES, cursors);
    scatter3<<<dim3(ent_blocks, 3), 256, 0, stream>>>(
        adj_rows, adj_cols, adj_vals, cnt_a, rank_a, cv_a,
        inc_cols, inc_rows, inc_vals, cnt_e, rank_e, cv_e,
        inc_rows, inc_cols, inc_vals, cnt_n, rank_n, cv_n, sd_e, NNZ);

    // 1) A = x@W00, B = x@W01 in ONE pass (B into d_out), LDS weight-stationary
    mfma_gemm2<<<gemm_blocks, 256, 0, stream>>>(x, Wp00, Wp01, A_bf, B_bf, N_NODES);

    // 2) FUSED: F = edge-branch(B)  ∥  C = sigmoid(gather_adj(A))
    //    (independent work co-scheduled; C_bf overlays dead rank arrays only)
    edge_adjC_fused<<<2 * row_blocks, 256, 0, stream>>>(
        sd_n, cv_n, cv_e, B_bf, F, sd_a, cv_a, A_bf, C_bf, N_NODES);

    // 3) E = gather_adj(C) -> fp32 in d_out (overwrites dead B region)
    gather_csr<<<row_blocks, 256, 0, stream>>>(sd_a, cv_a,
                                               C_bf, E, N_NODES, 0, 0);

    // 4) out = sigmoid(E @ W10 + F @ W11)  (split-bf16 MFMA, in-place on d_out)
    final_mfma<<<final_blocks, 256, 0, stream>>>(E, F, Wh10, Wl10, Wh11, Wl11,
                                                 (float*)d_out, N_NODES);
}

// Round 23
// 656.362 us; speedup vs baseline: 1.1371x; 1.1371x over previous
//
#include <hip/hip_runtime.h>
#include <math.h>

#define N_NODES 50000
#define N_EDGES 400000
#define CH      256
#define NNZ     800000

typedef short s16x8 __attribute__((ext_vector_type(8)));
typedef float f32x4 __attribute__((ext_vector_type(4)));

__device__ __forceinline__ float sigmoidf_(float x) {
    return 1.0f / (1.0f + __expf(-x));
}
__device__ __forceinline__ unsigned short f2bf(float f) {
    unsigned u = __float_as_uint(f);
    u = (u + 0x7FFFu + ((u >> 16) & 1u)) >> 16;   // RNE
    return (unsigned short)u;
}
__device__ __forceinline__ float bf2f(unsigned short h) {
    return __uint_as_float((unsigned)h << 16);
}
__device__ __forceinline__ f32x4 bfrow(ushort4 s) {
    f32x4 r;
    r.x = bf2f(s.x); r.y = bf2f(s.y); r.z = bf2f(s.z); r.w = bf2f(s.w);
    return r;
}

// ---------------------------------------------------------------------------
__global__ __launch_bounds__(256) void fill_i32(int* __restrict__ p, int val, int n)
{
    int stride = gridDim.x * 256;
    for (int i = blockIdx.x * 256 + threadIdx.x; i < n; i += stride) p[i] = val;
}

// --------------------- scan-free CSR build, rank/placement split ------------
__global__ __launch_bounds__(256) void hist_cvt(
    const int* __restrict__ k0, int* __restrict__ c0, int* __restrict__ r0,
    const int* __restrict__ k1, int* __restrict__ c1, int* __restrict__ r1,
    const int* __restrict__ k2, int* __restrict__ c2, int* __restrict__ r2, int n,
    const float* __restrict__ W00, const float* __restrict__ W01,
    const float* __restrict__ W10, const float* __restrict__ W11,
    unsigned short* __restrict__ Wp00, unsigned short* __restrict__ Wp01,
    unsigned short* __restrict__ Wh10, unsigned short* __restrict__ Wl10,
    unsigned short* __restrict__ Wh11, unsigned short* __restrict__ Wl11)
{
    int y = blockIdx.y;
    if (y < 3) {
        int i = blockIdx.x * 256 + threadIdx.x;
        if (i >= n) return;
        if      (y == 0) r0[i] = atomicAdd(&c0[k0[i]], 1);
        else if (y == 1) r1[i] = atomicAdd(&c1[k1[i]], 1);
        else             r2[i] = atomicAdd(&c2[k2[i]], 1);
        return;
    }
    int x = blockIdx.x;
    if (x >= 1024) return;
    int variant = x >> 8, nn = x & 255, k = threadIdx.x;
    int k0i = k >> 5, g = (k >> 3) & 3, j = k & 7;
    size_t o = (((size_t)(k0i * 4 + g)) * 256 + nn) * 8 + j;
    if (variant == 0) { Wp00[o] = f2bf(W00[k * 256 + nn]); return; }
    if (variant == 1) { Wp01[o] = f2bf(W01[k * 256 + nn]); return; }
    const float* W = (variant == 2) ? W10 : W11;
    unsigned short* Th = (variant == 2) ? Wh10 : Wh11;
    unsigned short* Tl = (variant == 2) ? Wl10 : Wl11;
    float w = W[k * 256 + nn];
    unsigned short h = f2bf(w);
    Th[o] = h;
    Tl[o] = f2bf(w - bf2f(h));
}

__global__ __launch_bounds__(256) void reserve3(
    int* __restrict__ c0, int* __restrict__ sd0, int n0,
    int* __restrict__ c1, int* __restrict__ sd1, int n1,
    int* __restrict__ c2, int* __restrict__ sd2, int n2,
    int* __restrict__ cursors)
{
    int y = blockIdx.y;
    int* cnt = (y == 0) ? c0 : (y == 1) ? c1 : c2;
    int* sd  = (y == 0) ? sd0 : (y == 1) ? sd1 : sd2;
    int  nk  = (y == 0) ? n0 : (y == 1) ? n1 : n2;
    int k = blockIdx.x * 256 + threadIdx.x;
    if (k >= nk) return;
    int deg  = cnt[k];
    int base = deg ? atomicAdd(&cursors[y], deg) : 0;
    sd[k]  = base | (deg << 20);
    cnt[k] = base;
}

__global__ __launch_bounds__(256) void scatter3(
    const int* __restrict__ k0, const int* __restrict__ o0, const float* __restrict__ v0,
    const int* __restrict__ c0, const int* __restrict__ r0, int2* __restrict__ cv0,
    const int* __restrict__ k1, const int* __restrict__ o1, const float* __restrict__ v1,
    const int* __restrict__ c1, const int* __restrict__ r1, int2* __restrict__ cv1,
    const int* __restrict__ k2, const int* __restrict__ o2, const float* __restrict__ v2,
    const int* __restrict__ c2, const int* __restrict__ r2, int2* __restrict__ cv2,
    const int* __restrict__ sd_e, int n)
{
    int i = blockIdx.x * 256 + threadIdx.x;
    if (i >= n) return;
    if (blockIdx.y == 0) {
        int pos = c0[k0[i]] + r0[i];
        cv0[pos] = make_int2(o0[i], __float_as_int(v0[i]));
    } else if (blockIdx.y == 1) {
        int pos = c1[k1[i]] + r1[i];
        cv1[pos] = make_int2(o1[i], __float_as_int(v1[i]));
    } else {
        int pos = c2[k2[i]] + r2[i];
        cv2[pos] = make_int2(sd_e[o2[i]], __float_as_int(v2[i]));  // pre-resolved
    }
}

// ---------------------------------------------------------------------------
// Fused dual-output MFMA GEMM, weight-stationary via LDS.
// ---------------------------------------------------------------------------
__global__ __launch_bounds__(256, 2) void mfma_gemm2(
    const float* __restrict__ X,
    const unsigned short* __restrict__ Wp0, const unsigned short* __restrict__ Wp1,
    unsigned short* __restrict__ Y0, unsigned short* __restrict__ Y1, int M)
{
    __shared__ unsigned short lds[2 * 4 * 257 * 8];   // 32896 B
    const int tid = threadIdx.x;
    const int wv = tid >> 6, lane = tid & 63;
    const int row0 = blockIdx.x * 64 + wv * 16;
    const int r = lane & 15, g = lane >> 4;

    f32x4 acc0[16], acc1[16];
#pragma unroll
    for (int t = 0; t < 16; t++) {
        acc0[t] = (f32x4){0.f, 0.f, 0.f, 0.f};
        acc1[t] = (f32x4){0.f, 0.f, 0.f, 0.f};
    }

    int arow = row0 + r; if (arow >= M) arow = M - 1;

    for (int k0i = 0; k0i < 8; ++k0i) {
        const float* xp = X + (size_t)arow * CH + k0i * 32 + g * 8;
        float4 f0 = *(const float4*)(xp);
        float4 f1 = *(const float4*)(xp + 4);

        if (k0i) __syncthreads();
#pragma unroll
        for (int m = 0; m < 2; m++) {
            const unsigned short* src = (m == 0) ? Wp0 : Wp1;
            src += (size_t)k0i * 1024 * 8;
#pragma unroll
            for (int g2 = 0; g2 < 4; g2++) {
                int frag = (m * 4 + g2) * 257 + tid;
                *(s16x8*)&lds[frag * 8] = *(const s16x8*)(src + (size_t)(g2 * 256 + tid) * 8);
            }
        }
        __syncthreads();

        s16x8 a;
        a[0] = f2bf(f0.x); a[1] = f2bf(f0.y); a[2] = f2bf(f0.z); a[3] = f2bf(f0.w);
        a[4] = f2bf(f1.x); a[5] = f2bf(f1.y); a[6] = f2bf(f1.z); a[7] = f2bf(f1.w);

#pragma unroll
        for (int t = 0; t < 16; t++) {
            int rr = t * 16 + r;
            s16x8 b0 = *(const s16x8*)&lds[((0 + g) * 257 + rr) * 8];
            s16x8 b1 = *(const s16x8*)&lds[((4 + g) * 257 + rr) * 8];
            acc0[t] = __builtin_amdgcn_mfma_f32_16x16x32_bf16(a, b0, acc0[t], 0, 0, 0);
            acc1[t] = __builtin_amdgcn_mfma_f32_16x16x32_bf16(a, b1, acc1[t], 0, 0, 0);
        }
    }

    const int drow0 = row0 + g * 4;
#pragma unroll
    for (int t = 0; t < 16; t++) {
        int col = t * 16 + r;
#pragma unroll
        for (int j = 0; j < 4; j++) {
            int dr = drow0 + j;
            if (dr < M) {
                Y0[(size_t)dr * CH + col] = f2bf(acc0[t][j]);
                Y1[(size_t)dr * CH + col] = f2bf(acc1[t][j]);
            }
        }
    }
}

// ---------------------------------------------------------------------------
// CSR gather SpMM (bf16 rows, packed int2 entries): O[r] = act( sum v*S[c] )
// ---------------------------------------------------------------------------
__global__ __launch_bounds__(256) void gather_csr(
    const int* __restrict__ sd, const int2* __restrict__ cv,
    const unsigned short* __restrict__ S,
    void* __restrict__ O, int n_rows, int sig, int out_bf)
{
    int r    = (int)((blockIdx.x * 256u + threadIdx.x) >> 6);
    int lane = threadIdx.x & 63;
    if (r >= n_rows) return;
    r = __builtin_amdgcn_readfirstlane(r);

    unsigned sdv = (unsigned)sd[r];
    int base = (int)(sdv & 0xFFFFFu), deg = (int)(sdv >> 20);
    const unsigned lb = (unsigned)lane << 3;
    const char* Sb = (const char*)S;

    f32x4 acc = (f32x4){0.f, 0.f, 0.f, 0.f};
    int i = 0;
    for (; i + 8 <= deg; i += 8) {
        int2 e[8]; ushort4 s[8];
#pragma unroll
        for (int q = 0; q < 8; q++) e[q] = cv[base + i + q];
#pragma unroll
        for (int q = 0; q < 8; q++)
            s[q] = *(const ushort4*)(Sb + (((unsigned)e[q].x << 9) + lb));
#pragma unroll
        for (int q = 0; q < 8; q++) {
            float v = __int_as_float(e[q].y);
            f32x4 vv = {v, v, v, v};
            acc = __builtin_elementwise_fma(vv, bfrow(s[q]), acc);
        }
    }
    for (; i + 4 <= deg; i += 4) {
        int2 e[4]; ushort4 s[4];
#pragma unroll
        for (int q = 0; q < 4; q++) e[q] = cv[base + i + q];
#pragma unroll
        for (int q = 0; q < 4; q++)
            s[q] = *(const ushort4*)(Sb + (((unsigned)e[q].x << 9) + lb));
#pragma unroll
        for (int q = 0; q < 4; q++) {
            float v = __int_as_float(e[q].y);
            f32x4 vv = {v, v, v, v};
            acc = __builtin_elementwise_fma(vv, bfrow(s[q]), acc);
        }
    }
    for (; i < deg; i++) {
        int2 e = cv[base + i];
        float v = __int_as_float(e.y);
        ushort4 s = *(const ushort4*)(Sb + (((unsigned)e.x << 9) + lb));
        f32x4 vv = {v, v, v, v};
        acc = __builtin_elementwise_fma(vv, bfrow(s), acc);
    }
    if (sig) {
        acc.x = sigmoidf_(acc.x); acc.y = sigmoidf_(acc.y);
        acc.z = sigmoidf_(acc.z); acc.w = sigmoidf_(acc.w);
    }
    if (out_bf) {
        ushort4 o; o.x = f2bf(acc.x); o.y = f2bf(acc.y); o.z = f2bf(acc.z); o.w = f2bf(acc.w);
        *(ushort4*)((char*)O + (((unsigned)r << 9) + lb)) = o;
    } else {
        *(f32x4*)((char*)O + (((unsigned)r << 10) + (lb << 1))) = acc;
    }
}

// ---------------------------------------------------------------------------
// Edge branch via double CSR, packed int2 entries, pre-resolved descriptors.
// ---------------------------------------------------------------------------
__global__ __launch_bounds__(256) void edge_gather_csr(
    const int* __restrict__ sd_n, const int2* __restrict__ cv_n,
    const int2* __restrict__ cv_e,
    const unsigned short* __restrict__ B, float* __restrict__ F, int n_nodes)
{
    int n    = (int)((blockIdx.x * 256u + threadIdx.x) >> 6);
    int lane = threadIdx.x & 63;
    if (n >= n_nodes) return;
    n = __builtin_amdgcn_readfirstlane(n);

    unsigned sdn = (unsigned)sd_n[n];
    int baseN = (int)(sdn & 0xFFFFFu), degN = (int)(sdn >> 20);
    const unsigned lb = (unsigned)lane << 3;
    const char* Bb = (const char*)B;

    f32x4 acc = (f32x4){0.f, 0.f, 0.f, 0.f};
    for (int i = 0; i < degN; i++) {
        int2 en = cv_n[baseN + i];
        unsigned sde = (unsigned)en.x;                 // pre-resolved descriptor
        float v = __int_as_float(en.y);
        int baseE = (int)(sde & 0xFFFFFu), degE = (int)(sde >> 20);

        f32x4 d = (f32x4){0.f, 0.f, 0.f, 0.f};
        int j = 0;
        for (; j + 2 <= degE; j += 2) {
            int2 e0 = cv_e[baseE + j], e1 = cv_e[baseE + j + 1];
            ushort4 b0 = *(const ushort4*)(Bb + (((unsigned)e0.x << 9) + lb));
            ushort4 b1 = *(const ushort4*)(Bb + (((unsigned)e1.x << 9) + lb));
            float u0 = __int_as_float(e0.y), u1 = __int_as_float(e1.y);
            f32x4 uv0 = {u0, u0, u0, u0};
            f32x4 uv1 = {u1, u1, u1, u1};
            d = __builtin_elementwise_fma(uv0, bfrow(b0), d);
            d = __builtin_elementwise_fma(uv1, bfrow(b1), d);
        }
        for (; j < degE; j++) {
            int2 e0 = cv_e[baseE + j];
            float u = __int_as_float(e0.y);
            ushort4 b = *(const ushort4*)(Bb + (((unsigned)e0.x << 9) + lb));
            f32x4 uv = {u, u, u, u};
            d = __builtin_elementwise_fma(uv, bfrow(b), d);
        }
        f32x4 sd4;
        sd4.x = sigmoidf_(d.x); sd4.y = sigmoidf_(d.y);
        sd4.z = sigmoidf_(d.z); sd4.w = sigmoidf_(d.w);
        f32x4 vv = {v, v, v, v};
        acc = __builtin_elementwise_fma(vv, sd4, acc);
    }
    *(f32x4*)((char*)F + (((unsigned)n << 10) + (lb << 1))) = acc;
}

// ---------------------------------------------------------------------------
// Final GEMM, split-bf16 MFMA, fp32-equivalent, weight-stationary via LDS.
// FULL unroll on the t-loop (rule #20: partial unroll demotes acc to scratch).
// ---------------------------------------------------------------------------
__device__ __forceinline__ void split8(float4 a, float4 b, s16x8& hi, s16x8& lo)
{
    float v[8] = {a.x, a.y, a.z, a.w, b.x, b.y, b.z, b.w};
#pragma unroll
    for (int i = 0; i < 8; i++) {
        unsigned short h = f2bf(v[i]);
        hi[i] = (short)h;
        lo[i] = (short)f2bf(v[i] - bf2f(h));
    }
}

__global__ __launch_bounds__(256, 2) void final_mfma(
    const float* __restrict__ E, const float* __restrict__ F,
    const unsigned short* __restrict__ Wh10, const unsigned short* __restrict__ Wl10,
    const unsigned short* __restrict__ Wh11, const unsigned short* __restrict__ Wl11,
    float* __restrict__ Y, int M)
{
    __shared__ unsigned short lds[4 * 4 * 257 * 8];   // 65792 B (2 blocks/CU)
    const int tid = threadIdx.x;
    const int wv = tid >> 6, lane = tid & 63;
    const int row0 = blockIdx.x * 128 + wv * 32;
    const int r = lane & 15, g = lane >> 4;

    f32x4 acc[2][16];
#pragma unroll
    for (int gr = 0; gr < 2; gr++)
#pragma unroll
        for (int t = 0; t < 16; t++) acc[gr][t] = (f32x4){0.f, 0.f, 0.f, 0.f};

    int ar0 = row0 + r;      if (ar0 >= M) ar0 = M - 1;
    int ar1 = row0 + 16 + r; if (ar1 >= M) ar1 = M - 1;

    for (int k0i = 0; k0i < 8; ++k0i) {
        const int kbase = k0i * 32 + g * 8;
        const float* p = E + (size_t)ar0 * CH + kbase;
        float4 e0a = *(const float4*)p, e0b = *(const float4*)(p + 4);
        p = E + (size_t)ar1 * CH + kbase;
        float4 e1a = *(const float4*)p, e1b = *(const float4*)(p + 4);
        p = F + (size_t)ar0 * CH + kbase;
        float4 f0a = *(const float4*)p, f0b = *(const float4*)(p + 4);
        p = F + (size_t)ar1 * CH + kbase;
        float4 f1a = *(const float4*)p, f1b = *(const float4*)(p + 4);

        if (k0i) __syncthreads();
#pragma unroll
        for (int m = 0; m < 4; m++) {
            const unsigned short* src =
                (m == 0) ? Wh10 : (m == 1) ? Wl10 : (m == 2) ? Wh11 : Wl11;
            src += (size_t)k0i * 1024 * 8;
#pragma unroll
            for (int g2 = 0; g2 < 4; g2++) {
                int frag = (m * 4 + g2) * 257 + tid;
                *(s16x8*)&lds[frag * 8] = *(const s16x8*)(src + (size_t)(g2 * 256 + tid) * 8);
            }
        }
        __syncthreads();

        s16x8 eh0, el0, eh1, el1, fh0, fl0, fh1, fl1;
        split8(e0a, e0b, eh0, el0);
        split8(e1a, e1b, eh1, el1);
        split8(f0a, f0b, fh0, fl0);
        split8(f1a, f1b, fh1, fl1);

#pragma unroll
        for (int t = 0; t < 16; t++) {
            int rr = t * 16 + r;
            s16x8 bh0 = *(const s16x8*)&lds[((0 + g) * 257 + rr) * 8];
            s16x8 bl0 = *(const s16x8*)&lds[((4 + g) * 257 + rr) * 8];
            s16x8 bh1 = *(const s16x8*)&lds[((8 + g) * 257 + rr) * 8];
            s16x8 bl1 = *(const s16x8*)&lds[((12 + g) * 257 + rr) * 8];

            acc[0][t] = __builtin_amdgcn_mfma_f32_16x16x32_bf16(eh0, bh0, acc[0][t], 0, 0, 0);
            acc[0][t] = __builtin_amdgcn_mfma_f32_16x16x32_bf16(el0, bh0, acc[0][t], 0, 0, 0);
            acc[0][t] = __builtin_amdgcn_mfma_f32_16x16x32_bf16(eh0, bl0, acc[0][t], 0, 0, 0);
            acc[0][t] = __builtin_amdgcn_mfma_f32_16x16x32_bf16(fh0, bh1, acc[0][t], 0, 0, 0);
            acc[0][t] = __builtin_amdgcn_mfma_f32_16x16x32_bf16(fl0, bh1, acc[0][t], 0, 0, 0);
            acc[0][t] = __builtin_amdgcn_mfma_f32_16x16x32_bf16(fh0, bl1, acc[0][t], 0, 0, 0);

            acc[1][t] = __builtin_amdgcn_mfma_f32_16x16x32_bf16(eh1, bh0, acc[1][t], 0, 0, 0);
            acc[1][t] = __builtin_amdgcn_mfma_f32_16x16x32_bf16(el1, bh0, acc[1][t], 0, 0, 0);
            acc[1][t] = __builtin_amdgcn_mfma_f32_16x16x32_bf16(eh1, bl0, acc[1][t], 0, 0, 0);
            acc[1][t] = __builtin_amdgcn_mfma_f32_16x16x32_bf16(fh1, bh1, acc[1][t], 0, 0, 0);
            acc[1][t] = __builtin_amdgcn_mfma_f32_16x16x32_bf16(fl1, bh1, acc[1][t], 0, 0, 0);
            acc[1][t] = __builtin_amdgcn_mfma_f32_16x16x32_bf16(fh1, bl1, acc[1][t], 0, 0, 0);
        }
    }

#pragma unroll
    for (int gr = 0; gr < 2; gr++) {
        const int drow0 = row0 + gr * 16 + g * 4;
#pragma unroll
        for (int t = 0; t < 16; t++) {
            int col = t * 16 + r;
#pragma unroll
            for (int j = 0; j < 4; j++) {
                int dr = drow0 + j;
                if (dr < M) Y[(size_t)dr * CH + col] = sigmoidf_(acc[gr][t][j]);
            }
        }
    }
}

// ---------------------------------------------------------------------------
extern "C" void kernel_launch(void* const* d_in, const int* in_sizes, int n_in,
                              void* d_out, int out_size, void* d_ws, size_t ws_size,
                              hipStream_t stream)
{
    const float* x        = (const float*)d_in[0];
    const int*   adj_rows = (const int*)  d_in[1];
    const int*   adj_cols = (const int*)  d_in[2];
    const float* adj_vals = (const float*)d_in[3];
    const int*   inc_rows = (const int*)  d_in[4];
    const int*   inc_cols = (const int*)  d_in[5];
    const float* inc_vals = (const float*)d_in[6];
    const float* W00      = (const float*)d_in[7];
    const float* W01      = (const float*)d_in[8];
    const float* W10      = (const float*)d_in[9];
    const float* W11      = (const float*)d_in[10];

    // -------- workspace layout (~110.4 MB; proven-safe < 114.26 MB) ---------
    const size_t SZ_AB = (size_t)N_NODES * CH * 2;    // 25.6 MB
    const size_t SZ_F  = (size_t)N_NODES * CH * 4;    // 51.2 MB
    char* ws = (char*)d_ws;
    size_t off = 0;
    unsigned short* A_bf = (unsigned short*)(ws + off); off += SZ_AB;
    float*          F    = (float*)(ws + off);          off += SZ_F;
    int*   sd_a  = (int*)(ws + off);  off += (size_t)N_NODES * 4;
    int2*  cv_a  = (int2*)(ws + off); off += (size_t)NNZ * 8;
    unsigned short* Wp00  = (unsigned short*)(ws + off); off += (size_t)CH * CH * 2;
    unsigned short* Wp01  = (unsigned short*)(ws + off); off += (size_t)CH * CH * 2;
    unsigned short* Wh10  = (unsigned short*)(ws + off); off += (size_t)CH * CH * 2;
    unsigned short* Wl10  = (unsigned short*)(ws + off); off += (size_t)CH * CH * 2;
    unsigned short* Wh11  = (unsigned short*)(ws + off); off += (size_t)CH * CH * 2;
    unsigned short* Wl11  = (unsigned short*)(ws + off); off += (size_t)CH * CH * 2;
    // scratch (26.2 MB): cnt+cursors / sd / cv / rank; C_bf overlays the rank
    // arrays (dead after scatter3). Serial schedule: step-2 reads of cv_n/cv_e
    // complete before step-3 writes C_bf — disjoint regions regardless.
    char* scratch = ws + off;
    int*   cnt_a   = (int*)(scratch);          // [N_NODES]
    int*   cnt_e   = cnt_a + N_NODES;          // [N_EDGES]
    int*   cnt_n   = cnt_e + N_EDGES;          // [N_NODES]
    int*   cursors = cnt_n + N_NODES;          // [64]
    int*   sd_n    = cursors + 64;             // [N_NODES]
    int*   sd_e    = sd_n + N_NODES;           // [N_EDGES]
    int2*  cv_n    = (int2*)(sd_e + N_EDGES);  // [NNZ] {descriptor, val}
    int2*  cv_e    = cv_n + NNZ;               // [NNZ] {node, val}
    int*   rank_a  = (int*)(cv_e + NNZ);       // [NNZ] — dead after scatter3
    int*   rank_e  = rank_a + NNZ;             // [NNZ]
    int*   rank_n  = rank_e + NNZ;             // [NNZ]
    unsigned short* C_bf = (unsigned short*)rank_a;   // overlays dead ranks
    unsigned short* B_bf = (unsigned short*)d_out;
    float* E = (float*)d_out;

    const int gemm_blocks  = (N_NODES + 63) / 64;          // 782
    const int final_blocks = (N_NODES + 127) / 128;        // 391
    const int row_blocks   = (N_NODES * 64 + 255) / 256;   // 12500
    const int ent_blocks   = (NNZ + 255) / 256;            // 3125
    const int key_blocks   = (N_EDGES + 255) / 256;        // 1563

    // 0) CSR build: zero cnt+cursors -> {hist(+rank) | cvt} -> reserve -> place
    fill_i32<<<1024, 256, 0, stream>>>(cnt_a, 0, N_NODES + N_EDGES + N_NODES + 64);
    hist_cvt<<<dim3(ent_blocks, 4), 256, 0, stream>>>(
        adj_rows, cnt_a, rank_a, inc_cols, cnt_e, rank_e, inc_rows, cnt_n, rank_n, NNZ,
        W00, W01, W10, W11, Wp00, Wp01, Wh10, Wl10, Wh11, Wl11);
    reserve3<<<dim3(key_blocks, 3), 256, 0, stream>>>(
        cnt_a, sd_a, N_NODES, cnt_e, sd_e, N_EDGES, cnt_n, sd_n, N_NODES, cursors);
    scatter3<<<dim3(ent_blocks, 3), 256, 0, stream>>>(
        adj_rows, adj_cols, adj_vals, cnt_a, rank_a, cv_a,
        inc_cols, inc_rows, inc_vals, cnt_e, rank_e, cv_e,
        inc_rows, inc_cols, inc_vals, cnt_n, rank_n, cv_n, sd_e, NNZ);

    // 1) A = x@W00, B = x@W01 in ONE pass (B into d_out), LDS weight-stationary
    mfma_gemm2<<<gemm_blocks, 256, 0, stream>>>(x, Wp00, Wp01, A_bf, B_bf, N_NODES);

    // 2) F[n] = sum v * sigmoid(D_e)  (double-CSR, packed entries) — SERIAL:
    //    fusing with step 3 thrashed L2 (R22: combined 51 MB working set, −13%)
    edge_gather_csr<<<row_blocks, 256, 0, stream>>>(sd_n, cv_n, cv_e,
                                                    B_bf, F, N_NODES);

    // 3) C = sigmoid(gather_adj(A)) -> bf16  (overlays dead rank arrays)
    gather_csr<<<row_blocks, 256, 0, stream>>>(sd_a, cv_a,
                                               A_bf, C_bf, N_NODES, 1, 1);

    // 4) E = gather_adj(C) -> fp32 in d_out (overwrites dead B region)
    gather_csr<<<row_blocks, 256, 0, stream>>>(sd_a, cv_a,
                                               C_bf, E, N_NODES, 0, 0);

    // 5) out = sigmoid(E @ W10 + F @ W11)  (split-bf16 MFMA, in-place on d_out)
    final_mfma<<<final_blocks, 256, 0, stream>>>(E, F, Wh10, Wl10, Wh11, Wl11,
                                                 (float*)d_out, N_NODES);
}